// Round 10
// baseline (238.235 us; speedup 1.0000x reference)
//
#include <hip/hip_runtime.h>
#include <stdint.h>

#define CCH 64
#define HWPIX 65536
#define NBINS 256

typedef float f4 __attribute__((ext_vector_type(4)));
typedef unsigned u32x4 __attribute__((ext_vector_type(4)));

// ws layout (float slots):
// [0    .. 1023] : dominant bins, int32, B*C entries
// [1024 .. 5119] : WcolT[o*64+c] = W1[o*64+c] * inv1[o]
// [5120 .. 5183] : base_pre[o]
// [5184 .. 5247] : w2[o]
// [5248 .. 5251] : scalars {inv2, beta2p, b2, s_empty}
// [5312 .. 5375] : s1[c]  = sigmoid for single-hit mask {c}
// [8192 ..12287] : s2[c1*64+c2] = sigmoid for two-hit mask {c1,c2}

// Merged precomp: one block, 256 threads. Wave 0 builds the BN-folded
// tables + scalars; then s1 (64 lanes) and s2 (all 256, 16 entries each).
__global__ __launch_bounds__(256) void prep_kernel(
    const float* __restrict__ w1, const float* __restrict__ b1,
    const float* __restrict__ g1, const float* __restrict__ be1,
    const float* __restrict__ m1, const float* __restrict__ v1,
    const float* __restrict__ w2, const float* __restrict__ b2,
    const float* __restrict__ g2, const float* __restrict__ be2,
    const float* __restrict__ m2, const float* __restrict__ v2,
    float* __restrict__ ws)
{
    int tid = threadIdx.x;
    if (tid < CCH) {
        int o = tid;
        float inv1 = g1[o] * rsqrtf(v1[o] + 1e-5f);
        float S = 0.f;
        for (int c = 0; c < CCH; ++c) S += w1[o * CCH + c];
        float beta1p = be1[o] - m1[o] * inv1;
        float base_pre = (S + b1[o]) * inv1 + beta1p;
        for (int c = 0; c < CCH; ++c) ws[1024 + o * CCH + c] = w1[o * CCH + c] * inv1;
        ws[5120 + o] = base_pre;
        float w2o = w2[o];
        ws[5184 + o] = w2o;
        float t = fmaxf(base_pre, 0.f) * w2o;
        #pragma unroll
        for (int off = 32; off > 0; off >>= 1) t += __shfl_down(t, off, 64);
        if (o == 0) {
            float inv2 = g2[0] * rsqrtf(v2[0] + 1e-5f);
            float beta2p = be2[0] - m2[0] * inv2;
            float z = (t + b2[0]) * inv2 + beta2p;
            ws[5248] = inv2;
            ws[5249] = beta2p;
            ws[5250] = b2[0];
            ws[5251] = 1.f / (1.f + expf(-z));
        }
    }
    __syncthreads();
    if (tid < CCH) {   // s1 table
        int c = tid;
        float t1 = 0.f;
        for (int oo = 0; oo < CCH; ++oo) {
            float acc = ws[5120 + oo] - ws[1024 + oo * CCH + c];
            t1 += fmaxf(acc, 0.f) * ws[5184 + oo];
        }
        float z = (t1 + ws[5250]) * ws[5248] + ws[5249];
        ws[5312 + c] = 1.f / (1.f + expf(-z));
    }
    // s2 table: 4096 entries, 16 per thread. Subtraction order matches the
    // runtime fallback loop: base - w[c1] - w[c2].
    for (int k = 0; k < 16; ++k) {
        int idx = (k << 8) + tid;
        int c1 = idx >> 6, c2 = idx & 63;
        float t = 0.f;
        for (int o = 0; o < CCH; ++o) {
            float acc = ws[5120 + o] - ws[1024 + o * CCH + c1] - ws[1024 + o * CCH + c2];
            t += fmaxf(acc, 0.f) * ws[5184 + o];
        }
        float z = (t + ws[5250]) * ws[5248] + ws[5249];
        ws[8192 + idx] = 1.f / (1.f + expf(-z));
    }
}

// One block per (b,c) image: 256-bin histogram + first-max argmax (R4 config).
__global__ __launch_bounds__(256) void hist_kernel(
    const float* __restrict__ x, int* __restrict__ dom)
{
    __shared__ unsigned h[16][NBINS + 1];
    __shared__ unsigned long long red[NBINS];
    int tid = threadIdx.x;
    const float4* xp = (const float4*)(x + (size_t)blockIdx.x * HWPIX);

    for (int i = tid; i < 16 * (NBINS + 1); i += 256) ((unsigned*)h)[i] = 0;
    __syncthreads();

    unsigned* hmine = h[tid >> 4];
    const float scale = 256.0f / 255.0f;
    #pragma unroll 4
    for (int t = 0; t < HWPIX / 4 / 256; ++t) {
        float4 v = xp[t * 256 + tid];
        float vv[4] = {v.x, v.y, v.z, v.w};
        #pragma unroll
        for (int j = 0; j < 4; ++j) {
            float f = vv[j];
            if (f >= 0.f && f <= 255.f) {
                int bi = (int)(f * scale);
                bi = bi > NBINS - 1 ? NBINS - 1 : bi;
                atomicAdd(&hmine[bi], 1u);
            }
        }
    }
    __syncthreads();

    unsigned cnt = 0;
    #pragma unroll
    for (int k = 0; k < 16; ++k) cnt += h[k][tid];
    red[tid] = ((unsigned long long)cnt << 32) | (unsigned)(NBINS - 1 - tid);
    __syncthreads();
    #pragma unroll
    for (int s = 128; s > 0; s >>= 1) {
        if (tid < s) {
            unsigned long long a = red[tid], b = red[tid + s];
            red[tid] = a > b ? a : b;
        }
        __syncthreads();
    }
    if (tid == 0) dom[blockIdx.x] = (NBINS - 1) - (int)(red[0] & 0xffffffffu);
}

// Register-resident main (R9 structure), PLAIN cached stores (NT A/B).
__global__ __launch_bounds__(256, 8) void main_kernel(
    const float* __restrict__ x, const float* __restrict__ ws,
    const int* __restrict__ dom, float* __restrict__ out)
{
    __shared__ unsigned pmlo[16][64];
    __shared__ unsigned pmhi[16][64];
    __shared__ float ss[64];

    int tid = threadIdx.x;
    int rc = (gridDim.x - 1) - blockIdx.x;   // reversed order: LLC-hot first
    int img = rc >> 10;
    int jc  = rc & 1023;                     // chunk within image
    int g   = tid >> 4;                      // channel group
    int col = tid & 15;                      // float4 column
    int px0 = col << 2;

    const f4* xb4 = (const f4*)(x + ((size_t)img << 22));
    f4*       ob4 = (f4*)(out + ((size_t)img << 22));
    size_t base = ((size_t)jc << 4) + col;

    f4 v0 = xb4[((size_t)(g     ) << 14) + base];
    f4 v1 = xb4[((size_t)(g + 16) << 14) + base];
    f4 v2 = xb4[((size_t)(g + 32) << 14) + base];
    f4 v3 = xb4[((size_t)(g + 48) << 14) + base];

    const int* domi = dom + img * CCH;
    float d0 = (float)domi[g];
    float d1 = (float)domi[g + 16];
    float d2 = (float)domi[g + 32];
    float d3 = (float)domi[g + 48];

    unsigned lo[4], hi[4];
    #pragma unroll
    for (int j = 0; j < 4; ++j) {
        unsigned l = 0, h = 0;
        l |= (unsigned)(v0[j] >= d0 && v0[j] < d0 + 1.0f) << g;
        l |= (unsigned)(v1[j] >= d1 && v1[j] < d1 + 1.0f) << (g + 16);
        h |= (unsigned)(v2[j] >= d2 && v2[j] < d2 + 1.0f) << g;
        h |= (unsigned)(v3[j] >= d3 && v3[j] < d3 + 1.0f) << (g + 16);
        lo[j] = l; hi[j] = h;
    }
    *(u32x4*)&pmlo[g][px0] = *(u32x4*)lo;
    *(u32x4*)&pmhi[g][px0] = *(u32x4*)hi;
    __syncthreads();

    if (tid < 64) {        // one lane per pixel: OR partials, sigmoid
        int px = tid;
        unsigned mlo = 0, mhi = 0;
        #pragma unroll
        for (int gg = 0; gg < 16; ++gg) {
            mlo |= pmlo[gg][px];
            mhi |= pmhi[gg][px];
        }
        unsigned long long m = ((unsigned long long)mhi << 32) | mlo;
        float s;
        if (m == 0ull) {
            s = ws[5251];
        } else {
            int c1 = __builtin_ctzll(m);
            unsigned long long r1 = m & (m - 1);
            if (r1 == 0ull) {
                s = ws[5312 + c1];
            } else {
                int c2 = __builtin_ctzll(r1);
                unsigned long long r2 = r1 & (r1 - 1);
                if (r2 == 0ull) {
                    s = ws[8192 + (c1 << 6) + c2];
                } else {
                    float t = 0.f;
                    for (int o = 0; o < CCH; ++o) {
                        float acc = ws[5120 + o];
                        unsigned long long mm = m;
                        const float* row = ws + 1024 + (o << 6);
                        while (mm) {
                            int c = __builtin_ctzll(mm);
                            mm &= mm - 1;
                            acc -= row[c];
                        }
                        t += fmaxf(acc, 0.f) * ws[5184 + o];
                    }
                    float z = (t + ws[5250]) * ws[5248] + ws[5249];
                    s = 1.f / (1.f + expf(-z));
                }
            }
        }
        ss[px] = s;
    }
    __syncthreads();

    f4 sv = *(const f4*)&ss[px0];
    v0 *= sv; v1 *= sv; v2 *= sv; v3 *= sv;
    ob4[((size_t)(g     ) << 14) + base] = v0;
    ob4[((size_t)(g + 16) << 14) + base] = v1;
    ob4[((size_t)(g + 32) << 14) + base] = v2;
    ob4[((size_t)(g + 48) << 14) + base] = v3;
}

extern "C" void kernel_launch(void* const* d_in, const int* in_sizes, int n_in,
                              void* d_out, int out_size, void* d_ws, size_t ws_size,
                              hipStream_t stream) {
    const float* x   = (const float*)d_in[0];
    const float* w1  = (const float*)d_in[1];
    const float* b1  = (const float*)d_in[2];
    const float* g1  = (const float*)d_in[3];
    const float* be1 = (const float*)d_in[4];
    const float* m1  = (const float*)d_in[5];
    const float* v1  = (const float*)d_in[6];
    const float* w2  = (const float*)d_in[7];
    const float* b2  = (const float*)d_in[8];
    const float* g2  = (const float*)d_in[9];
    const float* be2 = (const float*)d_in[10];
    const float* m2  = (const float*)d_in[11];
    const float* v2  = (const float*)d_in[12];

    float* ws  = (float*)d_ws;
    int*   dom = (int*)d_ws;                 // aliases ws[0..1023]
    float* outp = (float*)d_out;

    int B = in_sizes[0] / (CCH * HWPIX);     // 16

    prep_kernel<<<1, 256, 0, stream>>>(w1, b1, g1, be1, m1, v1,
                                       w2, b2, g2, be2, m2, v2, ws);
    hist_kernel<<<B * CCH, 256, 0, stream>>>(x, dom);
    main_kernel<<<B * 1024, 256, 0, stream>>>(x, ws, dom, outp);
}

// Round 11
// 215.335 us; speedup vs baseline: 1.1063x; 1.1063x over previous
//
#include <hip/hip_runtime.h>
#include <stdint.h>

#define CCH 64
#define HWPIX 65536
#define NBINS 256

typedef float f4 __attribute__((ext_vector_type(4)));

// ws layout (float slots):
// [0    .. 1023] : dominant bins, int32, B*C entries
// [1024 .. 5119] : WcolT[o*64+c] = W1[o*64+c] * inv1[o]
// [5120 .. 5183] : base_pre[o]
// [5184 .. 5247] : w2[o]
// [5248 .. 5251] : scalars {inv2, beta2p, b2, s_empty}
// [5312 .. 5375] : s1[c]  = sigmoid for single-hit mask {c}
// [8192 ..12287] : s2[c1*64+c2] = sigmoid for two-hit mask {c1,c2}

// Merged precomp: one block, 256 threads.
__global__ __launch_bounds__(256) void prep_kernel(
    const float* __restrict__ w1, const float* __restrict__ b1,
    const float* __restrict__ g1, const float* __restrict__ be1,
    const float* __restrict__ m1, const float* __restrict__ v1,
    const float* __restrict__ w2, const float* __restrict__ b2,
    const float* __restrict__ g2, const float* __restrict__ be2,
    const float* __restrict__ m2, const float* __restrict__ v2,
    float* __restrict__ ws)
{
    int tid = threadIdx.x;
    if (tid < CCH) {
        int o = tid;
        float inv1 = g1[o] * rsqrtf(v1[o] + 1e-5f);
        float S = 0.f;
        for (int c = 0; c < CCH; ++c) S += w1[o * CCH + c];
        float beta1p = be1[o] - m1[o] * inv1;
        float base_pre = (S + b1[o]) * inv1 + beta1p;
        for (int c = 0; c < CCH; ++c) ws[1024 + o * CCH + c] = w1[o * CCH + c] * inv1;
        ws[5120 + o] = base_pre;
        float w2o = w2[o];
        ws[5184 + o] = w2o;
        float t = fmaxf(base_pre, 0.f) * w2o;
        #pragma unroll
        for (int off = 32; off > 0; off >>= 1) t += __shfl_down(t, off, 64);
        if (o == 0) {
            float inv2 = g2[0] * rsqrtf(v2[0] + 1e-5f);
            float beta2p = be2[0] - m2[0] * inv2;
            float z = (t + b2[0]) * inv2 + beta2p;
            ws[5248] = inv2;
            ws[5249] = beta2p;
            ws[5250] = b2[0];
            ws[5251] = 1.f / (1.f + expf(-z));
        }
    }
    __syncthreads();
    if (tid < CCH) {   // s1 table
        int c = tid;
        float t1 = 0.f;
        for (int oo = 0; oo < CCH; ++oo) {
            float acc = ws[5120 + oo] - ws[1024 + oo * CCH + c];
            t1 += fmaxf(acc, 0.f) * ws[5184 + oo];
        }
        float z = (t1 + ws[5250]) * ws[5248] + ws[5249];
        ws[5312 + c] = 1.f / (1.f + expf(-z));
    }
    // s2 table: 4096 entries, 16 per thread; subtraction order matches the
    // runtime fallback loop: base - w[c1] - w[c2].
    for (int k = 0; k < 16; ++k) {
        int idx = (k << 8) + tid;
        int c1 = idx >> 6, c2 = idx & 63;
        float t = 0.f;
        for (int o = 0; o < CCH; ++o) {
            float acc = ws[5120 + o] - ws[1024 + o * CCH + c1] - ws[1024 + o * CCH + c2];
            t += fmaxf(acc, 0.f) * ws[5184 + o];
        }
        float z = (t + ws[5250]) * ws[5248] + ws[5249];
        ws[8192 + idx] = 1.f / (1.f + expf(-z));
    }
}

// One block per (b,c) image: 256-bin histogram + first-max argmax (R4 config).
__global__ __launch_bounds__(256) void hist_kernel(
    const float* __restrict__ x, int* __restrict__ dom)
{
    __shared__ unsigned h[16][NBINS + 1];
    __shared__ unsigned long long red[NBINS];
    int tid = threadIdx.x;
    const float4* xp = (const float4*)(x + (size_t)blockIdx.x * HWPIX);

    for (int i = tid; i < 16 * (NBINS + 1); i += 256) ((unsigned*)h)[i] = 0;
    __syncthreads();

    unsigned* hmine = h[tid >> 4];
    const float scale = 256.0f / 255.0f;
    #pragma unroll 4
    for (int t = 0; t < HWPIX / 4 / 256; ++t) {
        float4 v = xp[t * 256 + tid];
        float vv[4] = {v.x, v.y, v.z, v.w};
        #pragma unroll
        for (int j = 0; j < 4; ++j) {
            float f = vv[j];
            if (f >= 0.f && f <= 255.f) {
                int bi = (int)(f * scale);
                bi = bi > NBINS - 1 ? NBINS - 1 : bi;
                atomicAdd(&hmine[bi], 1u);
            }
        }
    }
    __syncthreads();

    unsigned cnt = 0;
    #pragma unroll
    for (int k = 0; k < 16; ++k) cnt += h[k][tid];
    red[tid] = ((unsigned long long)cnt << 32) | (unsigned)(NBINS - 1 - tid);
    __syncthreads();
    #pragma unroll
    for (int s = 128; s > 0; s >>= 1) {
        if (tid < s) {
            unsigned long long a = red[tid], b = red[tid + s];
            red[tid] = a > b ? a : b;
        }
        __syncthreads();
    }
    if (tid == 0) dom[blockIdx.x] = (NBINS - 1) - (int)(red[0] & 0xffffffffu);
}

// Barrier-free, LDS-free main. Wave owns a 16-px slab; lane (cb=l&15,
// pq=l>>4) holds channels {cb,cb+16,cb+32,cb+48} x 4 px in registers.
// Mask OR-reduce via 4 shfl_xor steps within 16-lane groups; sigmoid
// computed group-uniformly; NT stores. No __syncthreads anywhere.
__global__ __launch_bounds__(256, 8) void main_kernel(
    const float* __restrict__ x, const float* __restrict__ ws,
    const int* __restrict__ dom, float* __restrict__ out)
{
    int tid = threadIdx.x;
    int rc = (gridDim.x - 1) - blockIdx.x;   // reversed order: LLC-hot first
    int img = rc >> 10;
    int jc  = rc & 1023;                     // 64-px chunk within image
    int w   = tid >> 6;                      // wave -> 16-px slab
    int l   = tid & 63;
    int cb  = l & 15;                        // channel base
    int pq  = l >> 4;                        // px quad within slab

    const f4* xb4 = (const f4*)(x + ((size_t)img << 22));
    f4*       ob4 = (f4*)(out + ((size_t)img << 22));
    size_t base = ((size_t)jc << 4) + (w << 2) + pq;   // f4 index within channel

    f4 v0 = xb4[((size_t)(cb     ) << 14) + base];
    f4 v1 = xb4[((size_t)(cb + 16) << 14) + base];
    f4 v2 = xb4[((size_t)(cb + 32) << 14) + base];
    f4 v3 = xb4[((size_t)(cb + 48) << 14) + base];

    const int* domi = dom + img * CCH;
    float d0 = (float)domi[cb];
    float d1 = (float)domi[cb + 16];
    float d2 = (float)domi[cb + 32];
    float d3 = (float)domi[cb + 48];

    unsigned long long m[4];
    #pragma unroll
    for (int j = 0; j < 4; ++j) {
        unsigned lo = 0, hi = 0;
        lo |= (unsigned)(v0[j] >= d0 && v0[j] < d0 + 1.0f) << cb;
        lo |= (unsigned)(v1[j] >= d1 && v1[j] < d1 + 1.0f) << (cb + 16);
        hi |= (unsigned)(v2[j] >= d2 && v2[j] < d2 + 1.0f) << cb;
        hi |= (unsigned)(v3[j] >= d3 && v3[j] < d3 + 1.0f) << (cb + 16);
        m[j] = ((unsigned long long)hi << 32) | lo;
    }
    #pragma unroll
    for (int st = 1; st < 16; st <<= 1) {
        #pragma unroll
        for (int j = 0; j < 4; ++j)
            m[j] |= __shfl_xor(m[j], st, 64);
    }

    f4 sv;
    #pragma unroll
    for (int j = 0; j < 4; ++j) {
        unsigned long long mm0 = m[j];
        float s;
        if (mm0 == 0ull) {
            s = ws[5251];
        } else {
            int c1 = __builtin_ctzll(mm0);
            unsigned long long r1 = mm0 & (mm0 - 1);
            if (r1 == 0ull) {
                s = ws[5312 + c1];
            } else {
                int c2 = __builtin_ctzll(r1);
                unsigned long long r2 = r1 & (r1 - 1);
                if (r2 == 0ull) {
                    s = ws[8192 + (c1 << 6) + c2];
                } else {
                    float t = 0.f;
                    for (int o = 0; o < CCH; ++o) {
                        float acc = ws[5120 + o];
                        unsigned long long mm = mm0;
                        const float* row = ws + 1024 + (o << 6);
                        while (mm) {
                            int c = __builtin_ctzll(mm);
                            mm &= mm - 1;
                            acc -= row[c];
                        }
                        t += fmaxf(acc, 0.f) * ws[5184 + o];
                    }
                    float z = (t + ws[5250]) * ws[5248] + ws[5249];
                    s = 1.f / (1.f + expf(-z));
                }
            }
        }
        sv[j] = s;
    }

    v0 *= sv; v1 *= sv; v2 *= sv; v3 *= sv;
    __builtin_nontemporal_store(v0, &ob4[((size_t)(cb     ) << 14) + base]);
    __builtin_nontemporal_store(v1, &ob4[((size_t)(cb + 16) << 14) + base]);
    __builtin_nontemporal_store(v2, &ob4[((size_t)(cb + 32) << 14) + base]);
    __builtin_nontemporal_store(v3, &ob4[((size_t)(cb + 48) << 14) + base]);
}

extern "C" void kernel_launch(void* const* d_in, const int* in_sizes, int n_in,
                              void* d_out, int out_size, void* d_ws, size_t ws_size,
                              hipStream_t stream) {
    const float* x   = (const float*)d_in[0];
    const float* w1  = (const float*)d_in[1];
    const float* b1  = (const float*)d_in[2];
    const float* g1  = (const float*)d_in[3];
    const float* be1 = (const float*)d_in[4];
    const float* m1  = (const float*)d_in[5];
    const float* v1  = (const float*)d_in[6];
    const float* w2  = (const float*)d_in[7];
    const float* b2  = (const float*)d_in[8];
    const float* g2  = (const float*)d_in[9];
    const float* be2 = (const float*)d_in[10];
    const float* m2  = (const float*)d_in[11];
    const float* v2  = (const float*)d_in[12];

    float* ws  = (float*)d_ws;
    int*   dom = (int*)d_ws;                 // aliases ws[0..1023]
    float* outp = (float*)d_out;

    int B = in_sizes[0] / (CCH * HWPIX);     // 16

    prep_kernel<<<1, 256, 0, stream>>>(w1, b1, g1, be1, m1, v1,
                                       w2, b2, g2, be2, m2, v2, ws);
    hist_kernel<<<B * CCH, 256, 0, stream>>>(x, dom);
    main_kernel<<<B * 1024, 256, 0, stream>>>(x, ws, dom, outp);
}

// Round 12
// 202.591 us; speedup vs baseline: 1.1759x; 1.0629x over previous
//
#include <hip/hip_runtime.h>
#include <stdint.h>

#define CCH 64
#define HWPIX 65536
#define NBINS 256

typedef float f4 __attribute__((ext_vector_type(4)));
typedef unsigned u32x4 __attribute__((ext_vector_type(4)));

// ws layout (float slots):
// [0    .. 1023] : dominant bins, int32, B*C entries
// [1024 .. 5119] : WcolT[o*64+c] = W1[o*64+c] * inv1[o]
// [5120 .. 5183] : base_pre[o]
// [5184 .. 5247] : w2[o]
// [5248 .. 5251] : scalars {inv2, beta2p, b2, s_empty}
// [5312 .. 5375] : s1[c]  = sigmoid for single-hit mask {c}
// [8192 ..12287] : s2[c1*64+c2] = sigmoid for two-hit mask {c1,c2}

__global__ __launch_bounds__(256) void prep_kernel(
    const float* __restrict__ w1, const float* __restrict__ b1,
    const float* __restrict__ g1, const float* __restrict__ be1,
    const float* __restrict__ m1, const float* __restrict__ v1,
    const float* __restrict__ w2, const float* __restrict__ b2,
    const float* __restrict__ g2, const float* __restrict__ be2,
    const float* __restrict__ m2, const float* __restrict__ v2,
    float* __restrict__ ws)
{
    int tid = threadIdx.x;
    if (tid < CCH) {
        int o = tid;
        float inv1 = g1[o] * rsqrtf(v1[o] + 1e-5f);
        float S = 0.f;
        for (int c = 0; c < CCH; ++c) S += w1[o * CCH + c];
        float beta1p = be1[o] - m1[o] * inv1;
        float base_pre = (S + b1[o]) * inv1 + beta1p;
        for (int c = 0; c < CCH; ++c) ws[1024 + o * CCH + c] = w1[o * CCH + c] * inv1;
        ws[5120 + o] = base_pre;
        float w2o = w2[o];
        ws[5184 + o] = w2o;
        float t = fmaxf(base_pre, 0.f) * w2o;
        #pragma unroll
        for (int off = 32; off > 0; off >>= 1) t += __shfl_down(t, off, 64);
        if (o == 0) {
            float inv2 = g2[0] * rsqrtf(v2[0] + 1e-5f);
            float beta2p = be2[0] - m2[0] * inv2;
            float z = (t + b2[0]) * inv2 + beta2p;
            ws[5248] = inv2;
            ws[5249] = beta2p;
            ws[5250] = b2[0];
            ws[5251] = 1.f / (1.f + expf(-z));
        }
    }
    __syncthreads();
    if (tid < CCH) {   // s1 table
        int c = tid;
        float t1 = 0.f;
        for (int oo = 0; oo < CCH; ++oo) {
            float acc = ws[5120 + oo] - ws[1024 + oo * CCH + c];
            t1 += fmaxf(acc, 0.f) * ws[5184 + oo];
        }
        float z = (t1 + ws[5250]) * ws[5248] + ws[5249];
        ws[5312 + c] = 1.f / (1.f + expf(-z));
    }
    // s2 table: 4096 entries, 16 per thread; subtraction order matches the
    // runtime fallback loop: base - w[c1] - w[c2].
    for (int k = 0; k < 16; ++k) {
        int idx = (k << 8) + tid;
        int c1 = idx >> 6, c2 = idx & 63;
        float t = 0.f;
        for (int o = 0; o < CCH; ++o) {
            float acc = ws[5120 + o] - ws[1024 + o * CCH + c1] - ws[1024 + o * CCH + c2];
            t += fmaxf(acc, 0.f) * ws[5184 + o];
        }
        float z = (t + ws[5250]) * ws[5248] + ws[5249];
        ws[8192 + idx] = 1.f / (1.f + expf(-z));
    }
}

// One block per (b,c) image: 256-bin histogram + first-max argmax (R4 config).
__global__ __launch_bounds__(256) void hist_kernel(
    const float* __restrict__ x, int* __restrict__ dom)
{
    __shared__ unsigned h[16][NBINS + 1];
    __shared__ unsigned long long red[NBINS];
    int tid = threadIdx.x;
    const float4* xp = (const float4*)(x + (size_t)blockIdx.x * HWPIX);

    for (int i = tid; i < 16 * (NBINS + 1); i += 256) ((unsigned*)h)[i] = 0;
    __syncthreads();

    unsigned* hmine = h[tid >> 4];
    const float scale = 256.0f / 255.0f;
    #pragma unroll 4
    for (int t = 0; t < HWPIX / 4 / 256; ++t) {
        float4 v = xp[t * 256 + tid];
        float vv[4] = {v.x, v.y, v.z, v.w};
        #pragma unroll
        for (int j = 0; j < 4; ++j) {
            float f = vv[j];
            if (f >= 0.f && f <= 255.f) {
                int bi = (int)(f * scale);
                bi = bi > NBINS - 1 ? NBINS - 1 : bi;
                atomicAdd(&hmine[bi], 1u);
            }
        }
    }
    __syncthreads();

    unsigned cnt = 0;
    #pragma unroll
    for (int k = 0; k < 16; ++k) cnt += h[k][tid];
    red[tid] = ((unsigned long long)cnt << 32) | (unsigned)(NBINS - 1 - tid);
    __syncthreads();
    #pragma unroll
    for (int s = 128; s > 0; s >>= 1) {
        if (tid < s) {
            unsigned long long a = red[tid], b = red[tid + s];
            red[tid] = a > b ? a : b;
        }
        __syncthreads();
    }
    if (tid == 0) dom[blockIdx.x] = (NBINS - 1) - (int)(red[0] & 0xffffffffu);
}

// 2-chunk pipelined main: block owns two adjacent 64px chunks (A,B) of one
// image. All 8 f4 loads issued up front (2x MLP); masks in registers (int
// compare); ONE barrier; wave0 does sigmoid A while wave1 does sigmoid B;
// barrier; both chunks scaled + NT-stored. 2 barriers / 128 px.
__global__ __launch_bounds__(256, 4) void main_kernel(
    const float* __restrict__ x, const float* __restrict__ ws,
    const int* __restrict__ dom, float* __restrict__ out)
{
    __shared__ unsigned pmloA[16][64], pmhiA[16][64];
    __shared__ unsigned pmloB[16][64], pmhiB[16][64];
    __shared__ float ssA[64], ssB[64];

    int tid = threadIdx.x;
    int rc = (gridDim.x - 1) - blockIdx.x;   // reversed order: LLC-hot first
    int img = rc >> 9;
    int pr  = rc & 511;                      // chunk pair within image
    int jcA = pr << 1, jcB = jcA | 1;
    int g   = tid >> 4;                      // channel group
    int col = tid & 15;                      // float4 column
    int px0 = col << 2;

    const f4* xb4 = (const f4*)(x + ((size_t)img << 22));
    f4*       ob4 = (f4*)(out + ((size_t)img << 22));
    size_t baseA = ((size_t)jcA << 4) + col;
    size_t baseB = ((size_t)jcB << 4) + col;
    size_t ch0 = (size_t)(g     ) << 14;
    size_t ch1 = (size_t)(g + 16) << 14;
    size_t ch2 = (size_t)(g + 32) << 14;
    size_t ch3 = (size_t)(g + 48) << 14;

    // 8 independent b128 loads -> registers (2 chunks deep)
    f4 a0 = xb4[ch0 + baseA];
    f4 a1 = xb4[ch1 + baseA];
    f4 a2 = xb4[ch2 + baseA];
    f4 a3 = xb4[ch3 + baseA];
    f4 b0 = xb4[ch0 + baseB];
    f4 b1 = xb4[ch1 + baseB];
    f4 b2 = xb4[ch2 + baseB];
    f4 b3 = xb4[ch3 + baseB];

    const int* domi = dom + img * CCH;
    int id0 = domi[g];
    int id1 = domi[g + 16];
    int id2 = domi[g + 32];
    int id3 = domi[g + 48];

    unsigned loA[4], hiA[4], loB[4], hiB[4];
    #pragma unroll
    for (int j = 0; j < 4; ++j) {
        loA[j] = ((unsigned)((int)a0[j] == id0) << g)
               | ((unsigned)((int)a1[j] == id1) << (g + 16));
        hiA[j] = ((unsigned)((int)a2[j] == id2) << g)
               | ((unsigned)((int)a3[j] == id3) << (g + 16));
        loB[j] = ((unsigned)((int)b0[j] == id0) << g)
               | ((unsigned)((int)b1[j] == id1) << (g + 16));
        hiB[j] = ((unsigned)((int)b2[j] == id2) << g)
               | ((unsigned)((int)b3[j] == id3) << (g + 16));
    }
    *(u32x4*)&pmloA[g][px0] = *(u32x4*)loA;
    *(u32x4*)&pmhiA[g][px0] = *(u32x4*)hiA;
    *(u32x4*)&pmloB[g][px0] = *(u32x4*)loB;
    *(u32x4*)&pmhiB[g][px0] = *(u32x4*)hiB;
    __syncthreads();

    if (tid < 128) {       // wave0: chunk A, wave1: chunk B — in parallel
        int px = tid & 63;
        const unsigned (*plo)[64] = (tid < 64) ? pmloA : pmloB;
        const unsigned (*phi)[64] = (tid < 64) ? pmhiA : pmhiB;
        unsigned mlo = 0, mhi = 0;
        #pragma unroll
        for (int gg = 0; gg < 16; ++gg) {
            mlo |= plo[gg][px];
            mhi |= phi[gg][px];
        }
        unsigned long long m = ((unsigned long long)mhi << 32) | mlo;
        float s;
        if (m == 0ull) {
            s = ws[5251];
        } else {
            int c1 = __builtin_ctzll(m);
            unsigned long long r1 = m & (m - 1);
            if (r1 == 0ull) {
                s = ws[5312 + c1];
            } else {
                int c2 = __builtin_ctzll(r1);
                unsigned long long r2 = r1 & (r1 - 1);
                if (r2 == 0ull) {
                    s = ws[8192 + (c1 << 6) + c2];
                } else {
                    float t = 0.f;
                    for (int o = 0; o < CCH; ++o) {
                        float acc = ws[5120 + o];
                        unsigned long long mm = m;
                        const float* row = ws + 1024 + (o << 6);
                        while (mm) {
                            int c = __builtin_ctzll(mm);
                            mm &= mm - 1;
                            acc -= row[c];
                        }
                        t += fmaxf(acc, 0.f) * ws[5184 + o];
                    }
                    float z = (t + ws[5250]) * ws[5248] + ws[5249];
                    s = 1.f / (1.f + expf(-z));
                }
            }
        }
        if (tid < 64) ssA[px] = s; else ssB[px] = s;
    }
    __syncthreads();

    f4 svA = *(const f4*)&ssA[px0];
    f4 svB = *(const f4*)&ssB[px0];
    a0 *= svA; a1 *= svA; a2 *= svA; a3 *= svA;
    b0 *= svB; b1 *= svB; b2 *= svB; b3 *= svB;
    __builtin_nontemporal_store(a0, &ob4[ch0 + baseA]);
    __builtin_nontemporal_store(a1, &ob4[ch1 + baseA]);
    __builtin_nontemporal_store(a2, &ob4[ch2 + baseA]);
    __builtin_nontemporal_store(a3, &ob4[ch3 + baseA]);
    __builtin_nontemporal_store(b0, &ob4[ch0 + baseB]);
    __builtin_nontemporal_store(b1, &ob4[ch1 + baseB]);
    __builtin_nontemporal_store(b2, &ob4[ch2 + baseB]);
    __builtin_nontemporal_store(b3, &ob4[ch3 + baseB]);
}

extern "C" void kernel_launch(void* const* d_in, const int* in_sizes, int n_in,
                              void* d_out, int out_size, void* d_ws, size_t ws_size,
                              hipStream_t stream) {
    const float* x   = (const float*)d_in[0];
    const float* w1  = (const float*)d_in[1];
    const float* b1  = (const float*)d_in[2];
    const float* g1  = (const float*)d_in[3];
    const float* be1 = (const float*)d_in[4];
    const float* m1  = (const float*)d_in[5];
    const float* v1  = (const float*)d_in[6];
    const float* w2  = (const float*)d_in[7];
    const float* b2  = (const float*)d_in[8];
    const float* g2  = (const float*)d_in[9];
    const float* be2 = (const float*)d_in[10];
    const float* m2  = (const float*)d_in[11];
    const float* v2  = (const float*)d_in[12];

    float* ws  = (float*)d_ws;
    int*   dom = (int*)d_ws;                 // aliases ws[0..1023]
    float* outp = (float*)d_out;

    int B = in_sizes[0] / (CCH * HWPIX);     // 16

    prep_kernel<<<1, 256, 0, stream>>>(w1, b1, g1, be1, m1, v1,
                                       w2, b2, g2, be2, m2, v2, ws);
    hist_kernel<<<B * CCH, 256, 0, stream>>>(x, dom);
    main_kernel<<<B * 512, 256, 0, stream>>>(x, ws, dom, outp);
}